// Round 1
// baseline (3306.228 us; speedup 1.0000x reference)
//
#include <hip/hip_runtime.h>
#include <hip/hip_bf16.h>

typedef __bf16 bf16_t;
typedef __bf16 bf16x8 __attribute__((ext_vector_type(8)));
typedef float f32x4 __attribute__((ext_vector_type(4)));

#define B_ 16
#define S_ 1024
#define E_ 512
#define H_ 8
#define DH_ 64
#define L_ 6
#define F_ 2048
#define M_ (B_ * S_)   // 16384 rows

// ---------------- cast f32 -> bf16 (contiguous) ----------------
__global__ void cast_bf16_kernel(const float* __restrict__ src, bf16_t* __restrict__ dst, int n) {
    int i = (blockIdx.x * 256 + threadIdx.x) * 4;
    if (i + 3 < n) {
        f32x4 v = *(const f32x4*)&src[i];
        #pragma unroll
        for (int j = 0; j < 4; ++j) dst[i + j] = (bf16_t)v[j];
    }
}

// ------- cast + transpose: src [K,N] f32 -> dst [N,K] bf16, one matrix per blockIdx.z -------
__global__ void castT_kernel(const float* __restrict__ src, bf16_t* __restrict__ dst, int K, int N) {
    __shared__ bf16_t tile[32][33];
    size_t mo = (size_t)blockIdx.z * K * N;
    int k0 = blockIdx.y * 32, n0 = blockIdx.x * 32;
    int tx = threadIdx.x, ty = threadIdx.y;
    for (int i = ty; i < 32; i += 8)
        tile[i][tx] = (bf16_t)src[mo + (size_t)(k0 + i) * N + n0 + tx];
    __syncthreads();
    for (int i = ty; i < 32; i += 8)
        dst[mo + (size_t)(n0 + i) * K + k0 + tx] = tile[tx][i];
}

// ---------------- GEMM: C[M,N] = A[M,K](bf16) @ BT[N,K]^T (bf16) + bias ----------------
// EPI 0: out16 = (bf16)(acc+bias)            (optional RELU)
// EPI 1: v = acc+bias+pe[row>>10]; out32 = v; out16 = (bf16)v   (input projection)
// EPI 2: out32 = acc+bias+extra[row,col]                         (residual add)
template<int EPI, bool RELU>
__launch_bounds__(256, 2)
__global__ void gemm_kernel(const bf16_t* __restrict__ A, const bf16_t* __restrict__ BT,
                            const float* __restrict__ bias, float* __restrict__ out32,
                            bf16_t* __restrict__ out16, const float* __restrict__ extra,
                            int M, int N, int K)
{
    __shared__ bf16_t As[128][40];  // +8 pad breaks 8-way LDS bank conflicts
    __shared__ bf16_t Bs[128][40];
    const int tid = threadIdx.x;
    const int lane = tid & 63;
    const int w = tid >> 6;
    const int wm = w >> 1, wn = w & 1;          // wave -> 64x64 quadrant
    const int m0 = blockIdx.x * 128, n0 = blockIdx.y * 128;
    const int l15 = lane & 15, lg = lane >> 4;

    f32x4 acc[4][4] = {};

    for (int k0 = 0; k0 < K; k0 += 32) {
        __syncthreads();
        for (int c = tid; c < 512; c += 256) {
            int r = c >> 2, cc = (c & 3) << 3;
            *(bf16x8*)&As[r][cc] = *(const bf16x8*)&A[(size_t)(m0 + r) * K + k0 + cc];
            *(bf16x8*)&Bs[r][cc] = *(const bf16x8*)&BT[(size_t)(n0 + r) * K + k0 + cc];
        }
        __syncthreads();
        bf16x8 af[4], bfr[4];
        #pragma unroll
        for (int m = 0; m < 4; ++m) af[m] = *(const bf16x8*)&As[wm * 64 + m * 16 + l15][lg * 8];
        #pragma unroll
        for (int n = 0; n < 4; ++n) bfr[n] = *(const bf16x8*)&Bs[wn * 64 + n * 16 + l15][lg * 8];
        #pragma unroll
        for (int m = 0; m < 4; ++m)
            #pragma unroll
            for (int n = 0; n < 4; ++n)
                acc[m][n] = __builtin_amdgcn_mfma_f32_16x16x32_bf16(af[m], bfr[n], acc[m][n], 0, 0, 0);
    }

    #pragma unroll
    for (int m = 0; m < 4; ++m) {
        #pragma unroll
        for (int n = 0; n < 4; ++n) {
            int col = n0 + wn * 64 + n * 16 + l15;
            float bv = bias[col];
            #pragma unroll
            for (int r = 0; r < 4; ++r) {
                int row = m0 + wm * 64 + m * 16 + lg * 4 + r;   // C/D: row=(lane>>4)*4+reg, col=lane&15
                float v = acc[m][n][r] + bv;
                size_t idx = (size_t)row * N + col;
                if (EPI == 0) {
                    if (RELU) v = fmaxf(v, 0.f);
                    out16[idx] = (bf16_t)v;
                } else if (EPI == 1) {
                    v += extra[(size_t)(row >> 10) * E_ + col];   // pe[b] broadcast over seq
                    out32[idx] = v;
                    out16[idx] = (bf16_t)v;
                } else {
                    v += extra[idx];
                    out32[idx] = v;
                }
            }
        }
    }
}

// ---------------- V transpose: v[B*S, E] (per-head cols) -> vt[B,H,DH,S] ----------------
__launch_bounds__(256)
__global__ void transpose_v_kernel(const bf16_t* __restrict__ v, bf16_t* __restrict__ vt) {
    __shared__ bf16_t tile[64][72];
    int s0 = blockIdx.x * 64;
    int bh = blockIdx.y;
    int b = bh >> 3, h = bh & 7;
    int tid = threadIdx.x;
    for (int c = tid; c < 512; c += 256) {
        int r = c >> 3, cc = (c & 7) << 3;
        *(bf16x8*)&tile[r][cc] = *(const bf16x8*)&v[(size_t)(b * S_ + s0 + r) * E_ + h * DH_ + cc];
    }
    __syncthreads();
    for (int c = tid; c < 512; c += 256) {
        int d = c >> 3, cc = (c & 7) << 3;
        bf16x8 val;
        #pragma unroll
        for (int j = 0; j < 8; ++j) val[j] = tile[cc + j][d];
        *(bf16x8*)&vt[(size_t)(bh * DH_ + d) * S_ + s0 + cc] = val;
    }
}

// ---------------- flash attention: block = (b, h, 64 q-rows), 4 waves x 16 rows ----------------
__launch_bounds__(256, 2)
__global__ void attn_kernel(const bf16_t* __restrict__ q, const bf16_t* __restrict__ k,
                            const bf16_t* __restrict__ vt, bf16_t* __restrict__ o)
{
    const int qb = blockIdx.x, h = blockIdx.y, b = blockIdx.z;
    const int tid = threadIdx.x, lane = tid & 63, w = tid >> 6;
    const int l15 = lane & 15, lg = lane >> 4;
    const int q0 = qb * 64 + w * 16;
    __shared__ bf16_t plds[4][16][32];

    const size_t qoff = (size_t)(b * S_ + q0 + l15) * E_ + h * DH_;
    bf16x8 aq0 = *(const bf16x8*)&q[qoff + lg * 8];        // d in [0,32)
    bf16x8 aq1 = *(const bf16x8*)&q[qoff + 32 + lg * 8];   // d in [32,64)

    float mrow[4] = {-1e30f, -1e30f, -1e30f, -1e30f};
    float lrow[4] = {0.f, 0.f, 0.f, 0.f};
    f32x4 accO[4] = {};

    const bf16_t* kb = k + (size_t)b * S_ * E_ + h * DH_;
    const bf16_t* vb = vt + (size_t)(b * H_ + h) * DH_ * S_;

    for (int k0 = 0; k0 < S_; k0 += 32) {
        f32x4 sf[2];
        #pragma unroll
        for (int ks = 0; ks < 2; ++ks) {
            const bf16_t* kr = kb + (size_t)(k0 + ks * 16 + l15) * E_;
            bf16x8 bk0 = *(const bf16x8*)&kr[lg * 8];
            bf16x8 bk1 = *(const bf16x8*)&kr[32 + lg * 8];
            f32x4 s = {};
            s = __builtin_amdgcn_mfma_f32_16x16x32_bf16(aq0, bk0, s, 0, 0, 0);
            s = __builtin_amdgcn_mfma_f32_16x16x32_bf16(aq1, bk1, s, 0, 0, 0);
            #pragma unroll
            for (int r = 0; r < 4; ++r) sf[ks][r] = s[r] * 0.125f;  // 1/sqrt(64)
        }
        #pragma unroll
        for (int r = 0; r < 4; ++r) {
            float mx = fmaxf(sf[0][r], sf[1][r]);
            #pragma unroll
            for (int off = 8; off >= 1; off >>= 1) mx = fmaxf(mx, __shfl_xor(mx, off, 64));
            float mn = fmaxf(mrow[r], mx);
            float alpha = expf(mrow[r] - mn);
            float p0 = expf(sf[0][r] - mn);
            float p1 = expf(sf[1][r] - mn);
            float ps = p0 + p1;
            #pragma unroll
            for (int off = 8; off >= 1; off >>= 1) ps += __shfl_xor(ps, off, 64);
            lrow[r] = lrow[r] * alpha + ps;
            mrow[r] = mn;
            plds[w][lg * 4 + r][l15] = (bf16_t)p0;          // P in true (q_local, k_local) coords
            plds[w][lg * 4 + r][16 + l15] = (bf16_t)p1;
            #pragma unroll
            for (int dt = 0; dt < 4; ++dt) accO[dt][r] *= alpha;
        }
        __syncthreads();
        bf16x8 pa = *(const bf16x8*)&plds[w][l15][lg * 8];  // re-enter as A operand
        #pragma unroll
        for (int dt = 0; dt < 4; ++dt) {
            bf16x8 bvv = *(const bf16x8*)&vb[(size_t)(dt * 16 + l15) * S_ + k0 + lg * 8];
            accO[dt] = __builtin_amdgcn_mfma_f32_16x16x32_bf16(pa, bvv, accO[dt], 0, 0, 0);
        }
        __syncthreads();
    }
    #pragma unroll
    for (int dt = 0; dt < 4; ++dt) {
        #pragma unroll
        for (int r = 0; r < 4; ++r) {
            int qrow = q0 + lg * 4 + r;
            float ov = accO[dt][r] / lrow[r];
            o[(size_t)(b * S_ + qrow) * E_ + h * DH_ + dt * 16 + l15] = (bf16_t)ov;
        }
    }
}

// ---------------- layernorm (fp32 in, fp32 + bf16 out), one wave per row ----------------
__launch_bounds__(256)
__global__ void ln_kernel(const float* __restrict__ in, const float* __restrict__ g,
                          const float* __restrict__ be, float* __restrict__ out32,
                          bf16_t* __restrict__ out16)
{
    int row = blockIdx.x * 4 + (threadIdx.x >> 6);
    int lane = threadIdx.x & 63;
    const float* rp = in + (size_t)row * E_ + lane * 8;
    float x[8];
    *(f32x4*)&x[0] = *(const f32x4*)rp;
    *(f32x4*)&x[4] = *(const f32x4*)(rp + 4);
    float s = 0.f;
    #pragma unroll
    for (int j = 0; j < 8; ++j) s += x[j];
    #pragma unroll
    for (int off = 32; off >= 1; off >>= 1) s += __shfl_xor(s, off, 64);
    float mean = s * (1.f / E_);
    float vs = 0.f;
    #pragma unroll
    for (int j = 0; j < 8; ++j) { float d = x[j] - mean; vs += d * d; }
    #pragma unroll
    for (int off = 32; off >= 1; off >>= 1) vs += __shfl_xor(vs, off, 64);
    float rstd = rsqrtf(vs * (1.f / E_) + 1e-5f);
    #pragma unroll
    for (int j = 0; j < 8; ++j) {
        int col = lane * 8 + j;
        float y = (x[j] - mean) * rstd * g[col] + be[col];
        size_t idx = (size_t)row * E_ + col;
        out32[idx] = y;
        out16[idx] = (bf16_t)y;
    }
}

// ---------------- final: LN + [E,2] head, one wave per row ----------------
__launch_bounds__(256)
__global__ void final_kernel(const float* __restrict__ in, const float* __restrict__ g,
                             const float* __restrict__ be, const float* __restrict__ Wout,
                             const float* __restrict__ bout, float* __restrict__ out)
{
    int row = blockIdx.x * 4 + (threadIdx.x >> 6);
    int lane = threadIdx.x & 63;
    const float* rp = in + (size_t)row * E_ + lane * 8;
    float x[8];
    *(f32x4*)&x[0] = *(const f32x4*)rp;
    *(f32x4*)&x[4] = *(const f32x4*)(rp + 4);
    float s = 0.f;
    #pragma unroll
    for (int j = 0; j < 8; ++j) s += x[j];
    #pragma unroll
    for (int off = 32; off >= 1; off >>= 1) s += __shfl_xor(s, off, 64);
    float mean = s * (1.f / E_);
    float vs = 0.f;
    #pragma unroll
    for (int j = 0; j < 8; ++j) { float d = x[j] - mean; vs += d * d; }
    #pragma unroll
    for (int off = 32; off >= 1; off >>= 1) vs += __shfl_xor(vs, off, 64);
    float rstd = rsqrtf(vs * (1.f / E_) + 1e-5f);
    float p0 = 0.f, p1 = 0.f;
    #pragma unroll
    for (int j = 0; j < 8; ++j) {
        int col = lane * 8 + j;
        float y = (x[j] - mean) * rstd * g[col] + be[col];
        p0 += y * Wout[col * 2 + 0];
        p1 += y * Wout[col * 2 + 1];
    }
    #pragma unroll
    for (int off = 32; off >= 1; off >>= 1) { p0 += __shfl_xor(p0, off, 64); p1 += __shfl_xor(p1, off, 64); }
    if (lane == 0) {
        out[(size_t)row * 2 + 0] = p0 + bout[0];
        out[(size_t)row * 2 + 1] = p1 + bout[1];
    }
}

extern "C" void kernel_launch(void* const* d_in, const int* in_sizes, int n_in,
                              void* d_out, int out_size, void* d_ws, size_t ws_size,
                              hipStream_t stream)
{
    (void)in_sizes; (void)n_in; (void)out_size;
    const float* x    = (const float*)d_in[0];
    const float* Win  = (const float*)d_in[1];
    const float* b_in = (const float*)d_in[2];
    const float* pe   = (const float*)d_in[3];
    const float* Wq   = (const float*)d_in[4];
    const float* bq   = (const float*)d_in[5];
    const float* Wk   = (const float*)d_in[6];
    const float* bk   = (const float*)d_in[7];
    const float* Wv   = (const float*)d_in[8];
    const float* bv   = (const float*)d_in[9];
    const float* Wo   = (const float*)d_in[10];
    const float* bo   = (const float*)d_in[11];
    const float* g1   = (const float*)d_in[12];
    const float* be1  = (const float*)d_in[13];
    const float* W1   = (const float*)d_in[14];
    const float* b1   = (const float*)d_in[15];
    const float* W2   = (const float*)d_in[16];
    const float* b2   = (const float*)d_in[17];
    const float* g2   = (const float*)d_in[18];
    const float* be2  = (const float*)d_in[19];
    const float* gf   = (const float*)d_in[20];
    const float* bef  = (const float*)d_in[21];
    const float* Wout = (const float*)d_in[22];
    const float* bout = (const float*)d_in[23];

    char* p = (char*)d_ws;
    auto take = [&](size_t bytes) { char* r = p; p += (bytes + 255) & ~(size_t)255; return r; };

    bf16_t* xb   = (bf16_t*)take((size_t)M_ * 64 * 2);
    bf16_t* WinT = (bf16_t*)take((size_t)E_ * 64 * 2);
    bf16_t* WqT  = (bf16_t*)take((size_t)L_ * E_ * E_ * 2);
    bf16_t* WkT  = (bf16_t*)take((size_t)L_ * E_ * E_ * 2);
    bf16_t* WvT  = (bf16_t*)take((size_t)L_ * E_ * E_ * 2);
    bf16_t* WoT  = (bf16_t*)take((size_t)L_ * E_ * E_ * 2);
    bf16_t* W1T  = (bf16_t*)take((size_t)L_ * E_ * F_ * 2);
    bf16_t* W2T  = (bf16_t*)take((size_t)L_ * E_ * F_ * 2);
    float*  h32  = (float*)take((size_t)M_ * E_ * 4);
    bf16_t* hb16 = (bf16_t*)take((size_t)M_ * E_ * 2);
    bf16_t* qb16 = (bf16_t*)take((size_t)M_ * E_ * 2);
    bf16_t* kb16 = (bf16_t*)take((size_t)M_ * E_ * 2);
    bf16_t* vb16 = (bf16_t*)take((size_t)M_ * E_ * 2);
    bf16_t* vtb  = (bf16_t*)take((size_t)M_ * E_ * 2);
    bf16_t* ob16 = (bf16_t*)take((size_t)M_ * E_ * 2);
    float*  t32  = (float*)take((size_t)M_ * E_ * 4);
    float*  a32  = (float*)take((size_t)M_ * E_ * 4);
    bf16_t* ab16 = (bf16_t*)take((size_t)M_ * E_ * 2);
    bf16_t* f1b  = qb16;  // overlay: q/k/v/vt region (4 * M*E*2 == M*F*2) is dead during FFN

    if ((size_t)(p - (char*)d_ws) > ws_size) return;  // workspace too small -> fail visibly

    cast_bf16_kernel<<<dim3(M_ * 64 / 4 / 256), dim3(256), 0, stream>>>(x, xb, M_ * 64);
    castT_kernel<<<dim3(E_ / 32, 64 / 32, 1), dim3(32, 8), 0, stream>>>(Win, WinT, 64, E_);
    castT_kernel<<<dim3(E_ / 32, E_ / 32, L_), dim3(32, 8), 0, stream>>>(Wq, WqT, E_, E_);
    castT_kernel<<<dim3(E_ / 32, E_ / 32, L_), dim3(32, 8), 0, stream>>>(Wk, WkT, E_, E_);
    castT_kernel<<<dim3(E_ / 32, E_ / 32, L_), dim3(32, 8), 0, stream>>>(Wv, WvT, E_, E_);
    castT_kernel<<<dim3(E_ / 32, E_ / 32, L_), dim3(32, 8), 0, stream>>>(Wo, WoT, E_, E_);
    castT_kernel<<<dim3(F_ / 32, E_ / 32, L_), dim3(32, 8), 0, stream>>>(W1, W1T, E_, F_);
    castT_kernel<<<dim3(E_ / 32, F_ / 32, L_), dim3(32, 8), 0, stream>>>(W2, W2T, F_, E_);

    // input projection + pe (dual fp32/bf16 output)
    gemm_kernel<1, false><<<dim3(M_ / 128, E_ / 128), dim3(256), 0, stream>>>(
        xb, WinT, b_in, h32, hb16, pe, M_, E_, 64);

    for (int i = 0; i < L_; ++i) {
        const bf16_t* WqTi = WqT + (size_t)i * E_ * E_;
        const bf16_t* WkTi = WkT + (size_t)i * E_ * E_;
        const bf16_t* WvTi = WvT + (size_t)i * E_ * E_;
        const bf16_t* WoTi = WoT + (size_t)i * E_ * E_;
        const bf16_t* W1Ti = W1T + (size_t)i * E_ * F_;
        const bf16_t* W2Ti = W2T + (size_t)i * E_ * F_;

        gemm_kernel<0, false><<<dim3(M_ / 128, E_ / 128), dim3(256), 0, stream>>>(
            hb16, WqTi, bq + i * E_, nullptr, qb16, nullptr, M_, E_, E_);
        gemm_kernel<0, false><<<dim3(M_ / 128, E_ / 128), dim3(256), 0, stream>>>(
            hb16, WkTi, bk + i * E_, nullptr, kb16, nullptr, M_, E_, E_);
        gemm_kernel<0, false><<<dim3(M_ / 128, E_ / 128), dim3(256), 0, stream>>>(
            hb16, WvTi, bv + i * E_, nullptr, vb16, nullptr, M_, E_, E_);
        transpose_v_kernel<<<dim3(S_ / 64, B_ * H_), dim3(256), 0, stream>>>(vb16, vtb);
        attn_kernel<<<dim3(S_ / 64, H_, B_), dim3(256), 0, stream>>>(qb16, kb16, vtb, ob16);
        gemm_kernel<2, false><<<dim3(M_ / 128, E_ / 128), dim3(256), 0, stream>>>(
            ob16, WoTi, bo + i * E_, t32, nullptr, h32, M_, E_, E_);
        ln_kernel<<<dim3(M_ / 4), dim3(256), 0, stream>>>(t32, g1 + i * E_, be1 + i * E_, a32, ab16);
        gemm_kernel<0, true><<<dim3(M_ / 128, F_ / 128), dim3(256), 0, stream>>>(
            ab16, W1Ti, b1 + i * F_, nullptr, f1b, nullptr, M_, F_, E_);
        gemm_kernel<2, false><<<dim3(M_ / 128, E_ / 128), dim3(256), 0, stream>>>(
            f1b, W2Ti, b2 + i * E_, t32, nullptr, a32, M_, E_, F_);
        ln_kernel<<<dim3(M_ / 4), dim3(256), 0, stream>>>(t32, g2 + i * E_, be2 + i * E_, h32, hb16);
    }

    final_kernel<<<dim3(M_ / 4), dim3(256), 0, stream>>>(h32, gf, bef, Wout, bout, (float*)d_out);
}

// Round 4
// 2303.729 us; speedup vs baseline: 1.4352x; 1.4352x over previous
//
#include <hip/hip_runtime.h>
#include <hip/hip_bf16.h>

typedef __bf16 bf16_t;
typedef __bf16 bf16x8 __attribute__((ext_vector_type(8)));
typedef __bf16 bf16x4 __attribute__((ext_vector_type(4)));
typedef float f32x4 __attribute__((ext_vector_type(4)));

#define B_ 16
#define S_ 1024
#define E_ 512
#define H_ 8
#define DH_ 64
#define L_ 6
#define F_ 2048
#define M_ (B_ * S_)   // 16384 rows

#define EXP2F(x) __builtin_amdgcn_exp2f(x)

#define GLOAD_LDS16(gsrc, ldst) \
    __builtin_amdgcn_global_load_lds((const __attribute__((address_space(1))) void*)(gsrc), \
                                     (__attribute__((address_space(3))) void*)(ldst), 16, 0, 0)

// ---------------- cast f32 -> bf16 (contiguous) ----------------
__global__ void cast_bf16_kernel(const float* __restrict__ src, bf16_t* __restrict__ dst, int n) {
    int i = (blockIdx.x * 256 + threadIdx.x) * 4;
    if (i + 3 < n) {
        f32x4 v = *(const f32x4*)&src[i];
        #pragma unroll
        for (int j = 0; j < 4; ++j) dst[i + j] = (bf16_t)v[j];
    }
}

// ------- cast + transpose: src [K,N] f32 -> dst [N,K] bf16, one matrix per blockIdx.z -------
__global__ void castT_kernel(const float* __restrict__ src, bf16_t* __restrict__ dst, int K, int N) {
    __shared__ bf16_t tile[32][33];
    size_t mo = (size_t)blockIdx.z * K * N;
    int k0 = blockIdx.y * 32, n0 = blockIdx.x * 32;
    int tx = threadIdx.x, ty = threadIdx.y;
    for (int i = ty; i < 32; i += 8)
        tile[i][tx] = (bf16_t)src[mo + (size_t)(k0 + i) * N + n0 + tx];
    __syncthreads();
    for (int i = ty; i < 32; i += 8)
        dst[mo + (size_t)(n0 + i) * K + k0 + tx] = tile[tx][i];
}

// ---------------- GEMM (m97 structure): C[M,N] = A[M,K](bf16) @ BT[N,K]^T + bias ----------------
// EPI 0: out16 = (bf16)(acc+bias)             (optional RELU)
// EPI 1: v = acc+bias+pe[row>>10]; out32 = v; out16 = (bf16)v    (input projection)
// EPI 2: out32 = acc+bias+extra[row,col]                          (residual add)
// EPI 3: out16 is vt[B,H,DH,S]: transposed V write (bf16x4 along s)
template<int EPI, bool RELU>
__launch_bounds__(256, 2)
__global__ void gemm_kernel(const bf16_t* __restrict__ A, const bf16_t* __restrict__ BT,
                            const float* __restrict__ bias, float* __restrict__ out32,
                            bf16_t* __restrict__ out16, const float* __restrict__ extra,
                            int M, int N, int K)
{
    // [128][32] bf16: row stride 64B -> ds_read_b128 frag reads are bank-optimal (no pad!)
    __shared__ bf16_t As[2][128][32];
    __shared__ bf16_t Bs[2][128][32];
    const int tid = threadIdx.x;
    const int lane = tid & 63;
    const int w = tid >> 6;
    const int wm = w >> 1, wn = w & 1;
    const int m0 = blockIdx.x * 128, n0 = blockIdx.y * 128;
    const int l15 = lane & 15, lg = lane >> 4;

    // staging: wave w owns rows [w*32, w*32+32), 2 chunks of 16 rows; lane i -> row +i/4, col (i&3)*8
    const int srow = w * 32 + (lane >> 2);
    const int scol = (lane & 3) * 8;
    const bf16_t* Ab = A + (size_t)(m0 + srow) * K + scol;
    const bf16_t* Bb = BT + (size_t)(n0 + srow) * K + scol;

    f32x4 acc[4][4] = {};
    const int nt = K >> 5;

    #define STAGE(buf, t) do { \
        size_t ko_ = (size_t)(t) * 32; \
        _Pragma("unroll") \
        for (int j_ = 0; j_ < 2; ++j_) { \
            GLOAD_LDS16(Ab + (size_t)j_ * 16 * K + ko_, &As[buf][w * 32 + j_ * 16][0]); \
            GLOAD_LDS16(Bb + (size_t)j_ * 16 * K + ko_, &Bs[buf][w * 32 + j_ * 16][0]); \
        } } while (0)

    STAGE(0, 0);
    __syncthreads();   // compiler emits vmcnt(0) drain before s_barrier
    int cur = 0;
    for (int t = 0; t < nt; ++t) {
        if (t + 1 < nt) STAGE(cur ^ 1, t + 1);
        bf16x8 af[4], bfr[4];
        #pragma unroll
        for (int m = 0; m < 4; ++m) af[m] = *(const bf16x8*)&As[cur][wm * 64 + m * 16 + l15][lg * 8];
        #pragma unroll
        for (int n = 0; n < 4; ++n) bfr[n] = *(const bf16x8*)&Bs[cur][wn * 64 + n * 16 + l15][lg * 8];
        __builtin_amdgcn_s_setprio(1);
        #pragma unroll
        for (int m = 0; m < 4; ++m)
            #pragma unroll
            for (int n = 0; n < 4; ++n)
                acc[m][n] = __builtin_amdgcn_mfma_f32_16x16x32_bf16(af[m], bfr[n], acc[m][n], 0, 0, 0);
        __builtin_amdgcn_s_setprio(0);
        __syncthreads();
        cur ^= 1;
    }
    #undef STAGE

    #pragma unroll
    for (int m = 0; m < 4; ++m) {
        #pragma unroll
        for (int n = 0; n < 4; ++n) {
            int col = n0 + wn * 64 + n * 16 + l15;
            float bv = bias[col];
            if (EPI == 3) {
                int row0 = m0 + wm * 64 + m * 16 + lg * 4;
                int b = row0 >> 10, s0 = row0 & 1023;
                bf16x4 pk;
                #pragma unroll
                for (int r = 0; r < 4; ++r) pk[r] = (bf16_t)(acc[m][n][r] + bv);
                *(bf16x4*)&out16[((size_t)(b * H_ + (col >> 6)) * DH_ + (col & 63)) * S_ + s0] = pk;
            } else {
                #pragma unroll
                for (int r = 0; r < 4; ++r) {
                    int row = m0 + wm * 64 + m * 16 + lg * 4 + r;  // C/D: row=(lane>>4)*4+r, col=lane&15
                    float v = acc[m][n][r] + bv;
                    size_t idx = (size_t)row * N + col;
                    if (EPI == 0) {
                        if (RELU) v = fmaxf(v, 0.f);
                        out16[idx] = (bf16_t)v;
                    } else if (EPI == 1) {
                        v += extra[(size_t)(row >> 10) * E_ + col];   // pe[b] broadcast over seq
                        out32[idx] = v;
                        out16[idx] = (bf16_t)v;
                    } else {
                        v += extra[idx];
                        out32[idx] = v;
                    }
                }
            }
        }
    }
}

// ---------------- flash attention: block=(128 q, h, b), 4 waves x 32 q-rows, KVBLK=64, no barriers ----
__launch_bounds__(256)
__global__ void attn_kernel(const bf16_t* __restrict__ q, const bf16_t* __restrict__ k,
                            const bf16_t* __restrict__ vt, bf16_t* __restrict__ o)
{
    const int qb = blockIdx.x, h = blockIdx.y, b = blockIdx.z;
    const int tid = threadIdx.x, lane = tid & 63, w = tid >> 6;
    const int l15 = lane & 15, lg = lane >> 4;
    const int q0 = qb * 128 + w * 32;
    __shared__ char psh_all[4][4096];      // per-wave P tile: 32 q x 64 k bf16, XOR-swizzled rows
    char* psh = psh_all[w];

    bf16x8 aq[2][2];
    #pragma unroll
    for (int m = 0; m < 2; ++m) {
        const size_t qoff = (size_t)(b * S_ + q0 + m * 16 + l15) * E_ + h * DH_;
        aq[m][0] = *(const bf16x8*)&q[qoff + lg * 8];
        aq[m][1] = *(const bf16x8*)&q[qoff + 32 + lg * 8];
    }

    float mrow[2][4], lrow[2][4];
    #pragma unroll
    for (int m = 0; m < 2; ++m)
        #pragma unroll
        for (int r = 0; r < 4; ++r) { mrow[m][r] = -1e30f; lrow[m][r] = 0.f; }
    f32x4 accO[2][4] = {};

    const bf16_t* kb = k + (size_t)b * S_ * E_ + h * DH_;
    const bf16_t* vb = vt + (size_t)(b * H_ + h) * DH_ * S_;
    const float sc = 0.125f * 1.44269504f;   // 1/sqrt(DH) * log2(e): softmax in exp2 domain

    for (int k0 = 0; k0 < S_; k0 += 64) {
        f32x4 sf[2][4];
        #pragma unroll
        for (int n = 0; n < 4; ++n) {
            const bf16_t* kr = kb + (size_t)(k0 + n * 16 + l15) * E_;
            bf16x8 bk0 = *(const bf16x8*)&kr[lg * 8];
            bf16x8 bk1 = *(const bf16x8*)&kr[32 + lg * 8];
            __builtin_amdgcn_s_setprio(1);
            #pragma unroll
            for (int m = 0; m < 2; ++m) {
                f32x4 s = {};
                s = __builtin_amdgcn_mfma_f32_16x16x32_bf16(aq[m][0], bk0, s, 0, 0, 0);
                s = __builtin_amdgcn_mfma_f32_16x16x32_bf16(aq[m][1], bk1, s, 0, 0, 0);
                sf[m][n] = s;
            }
            __builtin_amdgcn_s_setprio(0);
        }
        #pragma unroll
        for (int m = 0; m < 2; ++m) {
            #pragma unroll
            for (int r = 0; r < 4; ++r) {
                float v0 = sf[m][0][r] * sc, v1 = sf[m][1][r] * sc;
                float v2 = sf[m][2][r] * sc, v3 = sf[m][3][r] * sc;
                float mx = fmaxf(fmaxf(v0, v1), fmaxf(v2, v3));
                #pragma unroll
                for (int off = 8; off >= 1; off >>= 1) mx = fmaxf(mx, __shfl_xor(mx, off, 64));
                float mn = fmaxf(mrow[m][r], mx);
                float al = EXP2F(mrow[m][r] - mn);
                float p0 = EXP2F(v0 - mn), p1 = EXP2F(v1 - mn);
                float p2 = EXP2F(v2 - mn), p3 = EXP2F(v3 - mn);
                float ps = p0 + p1 + p2 + p3;
                #pragma unroll
                for (int off = 8; off >= 1; off >>= 1) ps += __shfl_xor(ps, off, 64);
                lrow[m][r] = lrow[m][r] * al + ps;
                mrow[m][r] = mn;
                int qq = m * 16 + lg * 4 + r;
                int swz = (qq & 7) << 4;
                char* rowp = psh + qq * 128;   // 64 k * 2B per row
                *(bf16_t*)(rowp + ((l15 * 2) ^ swz)) = (bf16_t)p0;
                *(bf16_t*)(rowp + ((32 + l15 * 2) ^ swz)) = (bf16_t)p1;
                *(bf16_t*)(rowp + ((64 + l15 * 2) ^ swz)) = (bf16_t)p2;
                *(bf16_t*)(rowp + ((96 + l15 * 2) ^ swz)) = (bf16_t)p3;
                #pragma unroll
                for (int dt = 0; dt < 4; ++dt) accO[m][dt][r] *= al;
            }
        }
        asm volatile("" ::: "memory");   // order P ds_writes before pa ds_reads (same-wave LDS is in-order)
        bf16x8 pa[2][2];
        #pragma unroll
        for (int m = 0; m < 2; ++m) {
            int qq = m * 16 + l15;
            int swz = (qq & 7) << 4;
            pa[m][0] = *(const bf16x8*)(psh + qq * 128 + ((lg * 16) ^ swz));
            pa[m][1] = *(const bf16x8*)(psh + qq * 128 + ((64 + lg * 16) ^ swz));
        }
        __builtin_amdgcn_s_setprio(1);
        #pragma unroll
        for (int kk = 0; kk < 2; ++kk)
            #pragma unroll
            for (int dt = 0; dt < 4; ++dt) {
                bf16x8 bvv = *(const bf16x8*)&vb[(size_t)(dt * 16 + l15) * S_ + k0 + kk * 32 + lg * 8];
                #pragma unroll
                for (int m = 0; m < 2; ++m)
                    accO[m][dt] = __builtin_amdgcn_mfma_f32_16x16x32_bf16(pa[m][kk], bvv, accO[m][dt], 0, 0, 0);
            }
        __builtin_amdgcn_s_setprio(0);
    }

    #pragma unroll
    for (int m = 0; m < 2; ++m) {
        float rl[4];
        #pragma unroll
        for (int r = 0; r < 4; ++r) rl[r] = 1.f / lrow[m][r];
        #pragma unroll
        for (int dt = 0; dt < 4; ++dt)
            #pragma unroll
            for (int r = 0; r < 4; ++r) {
                int qrow = q0 + m * 16 + lg * 4 + r;
                o[(size_t)(b * S_ + qrow) * E_ + h * DH_ + dt * 16 + l15] = (bf16_t)(accO[m][dt][r] * rl[r]);
            }
    }
}

// ---------------- layernorm (fp32 in, fp32 + bf16 out), one wave per row ----------------
__launch_bounds__(256)
__global__ void ln_kernel(const float* __restrict__ in, const float* __restrict__ g,
                          const float* __restrict__ be, float* __restrict__ out32,
                          bf16_t* __restrict__ out16)
{
    int row = blockIdx.x * 4 + (threadIdx.x >> 6);
    int lane = threadIdx.x & 63;
    const float* rp = in + (size_t)row * E_ + lane * 8;
    float x[8];
    *(f32x4*)&x[0] = *(const f32x4*)rp;
    *(f32x4*)&x[4] = *(const f32x4*)(rp + 4);
    float s = 0.f;
    #pragma unroll
    for (int j = 0; j < 8; ++j) s += x[j];
    #pragma unroll
    for (int off = 32; off >= 1; off >>= 1) s += __shfl_xor(s, off, 64);
    float mean = s * (1.f / E_);
    float vs = 0.f;
    #pragma unroll
    for (int j = 0; j < 8; ++j) { float d = x[j] - mean; vs += d * d; }
    #pragma unroll
    for (int off = 32; off >= 1; off >>= 1) vs += __shfl_xor(vs, off, 64);
    float rstd = rsqrtf(vs * (1.f / E_) + 1e-5f);
    #pragma unroll
    for (int j = 0; j < 8; ++j) {
        int col = lane * 8 + j;
        float y = (x[j] - mean) * rstd * g[col] + be[col];
        size_t idx = (size_t)row * E_ + col;
        out32[idx] = y;
        out16[idx] = (bf16_t)y;
    }
}

// ---------------- final: LN + [E,2] head, one wave per row ----------------
__launch_bounds__(256)
__global__ void final_kernel(const float* __restrict__ in, const float* __restrict__ g,
                             const float* __restrict__ be, const float* __restrict__ Wout,
                             const float* __restrict__ bout, float* __restrict__ out)
{
    int row = blockIdx.x * 4 + (threadIdx.x >> 6);
    int lane = threadIdx.x & 63;
    const float* rp = in + (size_t)row * E_ + lane * 8;
    float x[8];
    *(f32x4*)&x[0] = *(const f32x4*)rp;
    *(f32x4*)&x[4] = *(const f32x4*)(rp + 4);
    float s = 0.f;
    #pragma unroll
    for (int j = 0; j < 8; ++j) s += x[j];
    #pragma unroll
    for (int off = 32; off >= 1; off >>= 1) s += __shfl_xor(s, off, 64);
    float mean = s * (1.f / E_);
    float vs = 0.f;
    #pragma unroll
    for (int j = 0; j < 8; ++j) { float d = x[j] - mean; vs += d * d; }
    #pragma unroll
    for (int off = 32; off >= 1; off >>= 1) vs += __shfl_xor(vs, off, 64);
    float rstd = rsqrtf(vs * (1.f / E_) + 1e-5f);
    float p0 = 0.f, p1 = 0.f;
    #pragma unroll
    for (int j = 0; j < 8; ++j) {
        int col = lane * 8 + j;
        float y = (x[j] - mean) * rstd * g[col] + be[col];
        p0 += y * Wout[col * 2 + 0];
        p1 += y * Wout[col * 2 + 1];
    }
    #pragma unroll
    for (int off = 32; off >= 1; off >>= 1) { p0 += __shfl_xor(p0, off, 64); p1 += __shfl_xor(p1, off, 64); }
    if (lane == 0) {
        out[(size_t)row * 2 + 0] = p0 + bout[0];
        out[(size_t)row * 2 + 1] = p1 + bout[1];
    }
}

extern "C" void kernel_launch(void* const* d_in, const int* in_sizes, int n_in,
                              void* d_out, int out_size, void* d_ws, size_t ws_size,
                              hipStream_t stream)
{
    (void)in_sizes; (void)n_in; (void)out_size;
    const float* x    = (const float*)d_in[0];
    const float* Win  = (const float*)d_in[1];
    const float* b_in = (const float*)d_in[2];
    const float* pe   = (const float*)d_in[3];
    const float* Wq   = (const float*)d_in[4];
    const float* bq   = (const float*)d_in[5];
    const float* Wk   = (const float*)d_in[6];
    const float* bk   = (const float*)d_in[7];
    const float* Wv   = (const float*)d_in[8];
    const float* bv   = (const float*)d_in[9];
    const float* Wo   = (const float*)d_in[10];
    const float* bo   = (const float*)d_in[11];
    const float* g1   = (const float*)d_in[12];
    const float* be1  = (const float*)d_in[13];
    const float* W1   = (const float*)d_in[14];
    const float* b1   = (const float*)d_in[15];
    const float* W2   = (const float*)d_in[16];
    const float* b2   = (const float*)d_in[17];
    const float* g2   = (const float*)d_in[18];
    const float* be2  = (const float*)d_in[19];
    const float* gf   = (const float*)d_in[20];
    const float* bef  = (const float*)d_in[21];
    const float* Wout = (const float*)d_in[22];
    const float* bout = (const float*)d_in[23];

    char* p = (char*)d_ws;
    auto take = [&](size_t bytes) { char* r = p; p += (bytes + 255) & ~(size_t)255; return r; };

    bf16_t* xb   = (bf16_t*)take((size_t)M_ * 64 * 2);
    bf16_t* WinT = (bf16_t*)take((size_t)E_ * 64 * 2);
    bf16_t* WqT  = (bf16_t*)take((size_t)L_ * E_ * E_ * 2);
    bf16_t* WkT  = (bf16_t*)take((size_t)L_ * E_ * E_ * 2);
    bf16_t* WvT  = (bf16_t*)take((size_t)L_ * E_ * E_ * 2);
    bf16_t* WoT  = (bf16_t*)take((size_t)L_ * E_ * E_ * 2);
    bf16_t* W1T  = (bf16_t*)take((size_t)L_ * E_ * F_ * 2);
    bf16_t* W2T  = (bf16_t*)take((size_t)L_ * E_ * F_ * 2);
    float*  h32  = (float*)take((size_t)M_ * E_ * 4);
    bf16_t* hb16 = (bf16_t*)take((size_t)M_ * E_ * 2);
    bf16_t* qb16 = (bf16_t*)take((size_t)M_ * E_ * 2);
    bf16_t* kb16 = (bf16_t*)take((size_t)M_ * E_ * 2);
    bf16_t* vtb  = (bf16_t*)take((size_t)M_ * E_ * 2);
    bf16_t* ob16 = (bf16_t*)take((size_t)M_ * E_ * 2);
    float*  t32  = (float*)take((size_t)M_ * E_ * 4);
    float*  a32  = (float*)take((size_t)M_ * E_ * 4);
    bf16_t* ab16 = (bf16_t*)take((size_t)M_ * E_ * 2);
    // overlay: q/k/vt/o (4 * M*E*2 == M*F*2 = 64MB, contiguous takes) are dead during the FFN
    bf16_t* f1b  = qb16;

    if ((size_t)(p - (char*)d_ws) > ws_size) return;

    cast_bf16_kernel<<<dim3(M_ * 64 / 4 / 256), dim3(256), 0, stream>>>(x, xb, M_ * 64);
    castT_kernel<<<dim3(E_ / 32, 64 / 32, 1), dim3(32, 8), 0, stream>>>(Win, WinT, 64, E_);
    castT_kernel<<<dim3(E_ / 32, E_ / 32, L_), dim3(32, 8), 0, stream>>>(Wq, WqT, E_, E_);
    castT_kernel<<<dim3(E_ / 32, E_ / 32, L_), dim3(32, 8), 0, stream>>>(Wk, WkT, E_, E_);
    castT_kernel<<<dim3(E_ / 32, E_ / 32, L_), dim3(32, 8), 0, stream>>>(Wv, WvT, E_, E_);
    castT_kernel<<<dim3(E_ / 32, E_ / 32, L_), dim3(32, 8), 0, stream>>>(Wo, WoT, E_, E_);
    castT_kernel<<<dim3(F_ / 32, E_ / 32, L_), dim3(32, 8), 0, stream>>>(W1, W1T, E_, F_);
    castT_kernel<<<dim3(E_ / 32, F_ / 32, L_), dim3(32, 8), 0, stream>>>(W2, W2T, F_, E_);

    gemm_kernel<1, false><<<dim3(M_ / 128, E_ / 128), dim3(256), 0, stream>>>(
        xb, WinT, b_in, h32, hb16, pe, M_, E_, 64);

    for (int i = 0; i < L_; ++i) {
        const bf16_t* WqTi = WqT + (size_t)i * E_ * E_;
        const bf16_t* WkTi = WkT + (size_t)i * E_ * E_;
        const bf16_t* WvTi = WvT + (size_t)i * E_ * E_;
        const bf16_t* WoTi = WoT + (size_t)i * E_ * E_;
        const bf16_t* W1Ti = W1T + (size_t)i * E_ * F_;
        const bf16_t* W2Ti = W2T + (size_t)i * E_ * F_;

        gemm_kernel<0, false><<<dim3(M_ / 128, E_ / 128), dim3(256), 0, stream>>>(
            hb16, WqTi, bq + i * E_, nullptr, qb16, nullptr, M_, E_, E_);
        gemm_kernel<0, false><<<dim3(M_ / 128, E_ / 128), dim3(256), 0, stream>>>(
            hb16, WkTi, bk + i * E_, nullptr, kb16, nullptr, M_, E_, E_);
        gemm_kernel<3, false><<<dim3(M_ / 128, E_ / 128), dim3(256), 0, stream>>>(
            hb16, WvTi, bv + i * E_, nullptr, vtb, nullptr, M_, E_, E_);
        attn_kernel<<<dim3(S_ / 128, H_, B_), dim3(256), 0, stream>>>(qb16, kb16, vtb, ob16);
        gemm_kernel<2, false><<<dim3(M_ / 128, E_ / 128), dim3(256), 0, stream>>>(
            ob16, WoTi, bo + i * E_, t32, nullptr, h32, M_, E_, E_);
        ln_kernel<<<dim3(M_ / 4), dim3(256), 0, stream>>>(t32, g1 + i * E_, be1 + i * E_, a32, ab16);
        gemm_kernel<0, true><<<dim3(M_ / 128, F_ / 128), dim3(256), 0, stream>>>(
            ab16, W1Ti, b1 + i * F_, nullptr, f1b, nullptr, M_, F_, E_);
        gemm_kernel<2, false><<<dim3(M_ / 128, E_ / 128), dim3(256), 0, stream>>>(
            f1b, W2Ti, b2 + i * E_, t32, nullptr, a32, M_, E_, F_);
        ln_kernel<<<dim3(M_ / 4), dim3(256), 0, stream>>>(t32, g2 + i * E_, be2 + i * E_, h32, hb16);
    }

    final_kernel<<<dim3(M_ / 4), dim3(256), 0, stream>>>(h32, gf, bef, Wout, bout, (float*)d_out);
}

// Round 5
// 2221.246 us; speedup vs baseline: 1.4885x; 1.0371x over previous
//
#include <hip/hip_runtime.h>
#include <hip/hip_bf16.h>

typedef __bf16 bf16_t;
typedef __bf16 bf16x8 __attribute__((ext_vector_type(8)));
typedef __bf16 bf16x4 __attribute__((ext_vector_type(4)));
typedef float f32x4 __attribute__((ext_vector_type(4)));

#define B_ 16
#define S_ 1024
#define E_ 512
#define H_ 8
#define DH_ 64
#define L_ 6
#define F_ 2048
#define M_ (B_ * S_)   // 16384 rows

#define EXP2F(x) __builtin_amdgcn_exp2f(x)

#define GLOAD_LDS16(gsrc, ldst) \
    __builtin_amdgcn_global_load_lds((const __attribute__((address_space(1))) void*)(gsrc), \
                                     (__attribute__((address_space(3))) void*)(ldst), 16, 0, 0)

// ---------------- cast f32 -> bf16 (contiguous) ----------------
__global__ void cast_bf16_kernel(const float* __restrict__ src, bf16_t* __restrict__ dst, int n) {
    int i = (blockIdx.x * 256 + threadIdx.x) * 4;
    if (i + 3 < n) {
        f32x4 v = *(const f32x4*)&src[i];
        #pragma unroll
        for (int j = 0; j < 4; ++j) dst[i + j] = (bf16_t)v[j];
    }
}

// ------- cast + transpose: src [K,N] f32 -> dst [N,K] bf16, one matrix per blockIdx.z -------
__global__ void castT_kernel(const float* __restrict__ src, bf16_t* __restrict__ dst, int K, int N) {
    __shared__ bf16_t tile[32][33];
    size_t mo = (size_t)blockIdx.z * K * N;
    int k0 = blockIdx.y * 32, n0 = blockIdx.x * 32;
    int tx = threadIdx.x, ty = threadIdx.y;
    for (int i = ty; i < 32; i += 8)
        tile[i][tx] = (bf16_t)src[mo + (size_t)(k0 + i) * N + n0 + tx];
    __syncthreads();
    for (int i = ty; i < 32; i += 8)
        dst[mo + (size_t)(n0 + i) * K + k0 + tx] = tile[tx][i];
}

// ---------------- GEMM (m97 structure): C[M,N] = A[M,K](bf16) @ BT[N,K]^T + bias ----------------
// EPI 0: out16 = (bf16)(acc+bias)             (optional RELU)
// EPI 1: v = acc+bias+pe[row>>10]; out32 = v; out16 = (bf16)v    (input projection)
// EPI 2: out32 = acc+bias+extra[row,col]                          (residual add)
// EPI 3: out16 is vt[B,H,DH,S]: transposed V write (bf16x4 along s)
template<int EPI, bool RELU>
__launch_bounds__(256, 2)
__global__ void gemm_kernel(const bf16_t* __restrict__ A, const bf16_t* __restrict__ BT,
                            const float* __restrict__ bias, float* __restrict__ out32,
                            bf16_t* __restrict__ out16, const float* __restrict__ extra,
                            int M, int N, int K)
{
    // [128][32] bf16: row stride 64B -> ds_read_b128 frag reads are bank-optimal (no pad!)
    __shared__ bf16_t As[2][128][32];
    __shared__ bf16_t Bs[2][128][32];
    const int tid = threadIdx.x;
    const int lane = tid & 63;
    const int w = tid >> 6;
    const int wm = w >> 1, wn = w & 1;
    const int m0 = blockIdx.x * 128, n0 = blockIdx.y * 128;
    const int l15 = lane & 15, lg = lane >> 4;

    const int srow = w * 32 + (lane >> 2);
    const int scol = (lane & 3) * 8;
    const bf16_t* Ab = A + (size_t)(m0 + srow) * K + scol;
    const bf16_t* Bb = BT + (size_t)(n0 + srow) * K + scol;

    f32x4 acc[4][4] = {};
    const int nt = K >> 5;

    #define STAGE(buf, t) do { \
        size_t ko_ = (size_t)(t) * 32; \
        _Pragma("unroll") \
        for (int j_ = 0; j_ < 2; ++j_) { \
            GLOAD_LDS16(Ab + (size_t)j_ * 16 * K + ko_, &As[buf][w * 32 + j_ * 16][0]); \
            GLOAD_LDS16(Bb + (size_t)j_ * 16 * K + ko_, &Bs[buf][w * 32 + j_ * 16][0]); \
        } } while (0)

    STAGE(0, 0);
    __syncthreads();
    int cur = 0;
    for (int t = 0; t < nt; ++t) {
        if (t + 1 < nt) STAGE(cur ^ 1, t + 1);
        bf16x8 af[4], bfr[4];
        #pragma unroll
        for (int m = 0; m < 4; ++m) af[m] = *(const bf16x8*)&As[cur][wm * 64 + m * 16 + l15][lg * 8];
        #pragma unroll
        for (int n = 0; n < 4; ++n) bfr[n] = *(const bf16x8*)&Bs[cur][wn * 64 + n * 16 + l15][lg * 8];
        __builtin_amdgcn_s_setprio(1);
        #pragma unroll
        for (int m = 0; m < 4; ++m)
            #pragma unroll
            for (int n = 0; n < 4; ++n)
                acc[m][n] = __builtin_amdgcn_mfma_f32_16x16x32_bf16(af[m], bfr[n], acc[m][n], 0, 0, 0);
        __builtin_amdgcn_s_setprio(0);
        __syncthreads();
        cur ^= 1;
    }
    #undef STAGE

    #pragma unroll
    for (int m = 0; m < 4; ++m) {
        #pragma unroll
        for (int n = 0; n < 4; ++n) {
            int col = n0 + wn * 64 + n * 16 + l15;
            float bv = bias[col];
            if (EPI == 3) {
                int row0 = m0 + wm * 64 + m * 16 + lg * 4;
                int b = row0 >> 10, s0 = row0 & 1023;
                bf16x4 pk;
                #pragma unroll
                for (int r = 0; r < 4; ++r) pk[r] = (bf16_t)(acc[m][n][r] + bv);
                *(bf16x4*)&out16[((size_t)(b * H_ + (col >> 6)) * DH_ + (col & 63)) * S_ + s0] = pk;
            } else {
                #pragma unroll
                for (int r = 0; r < 4; ++r) {
                    int row = m0 + wm * 64 + m * 16 + lg * 4 + r;  // C/D: row=(lane>>4)*4+r, col=lane&15
                    float v = acc[m][n][r] + bv;
                    size_t idx = (size_t)row * N + col;
                    if (EPI == 0) {
                        if (RELU) v = fmaxf(v, 0.f);
                        out16[idx] = (bf16_t)v;
                    } else if (EPI == 1) {
                        v += extra[(size_t)(row >> 10) * E_ + col];   // pe[b] broadcast over seq
                        out32[idx] = v;
                        out16[idx] = (bf16_t)v;
                    } else {
                        v += extra[idx];
                        out32[idx] = v;
                    }
                }
            }
        }
    }
}

// ---------------- flash attention, swapped-operand (S^T) form ----------------
// block = 128 q rows of one (b,h); 4 waves x 32 q-rows; KVBLK=64; no barriers.
// XCD-grouped 1D grid: id = ((bh&15)*8 + qb)*8 + (bh>>4)  -> all 8 qb of a bh on one XCD, consecutive.
__launch_bounds__(256, 4)
__global__ void attn_kernel(const bf16_t* __restrict__ q, const bf16_t* __restrict__ k,
                            const bf16_t* __restrict__ vt, bf16_t* __restrict__ o)
{
    const int id = blockIdx.x;
    const int bh_hi = id & 7;
    const int rest = id >> 3;
    const int qb = rest & 7;
    const int bh = bh_hi * 16 + (rest >> 3);
    const int b = bh >> 3, h = bh & 7;
    const int tid = threadIdx.x, lane = tid & 63, w = tid >> 6;
    const int l15 = lane & 15, lg = lane >> 4;
    const int q0 = qb * 128 + w * 32;
    __shared__ char psh_all[4][4096];      // per-wave P tile: 32 q x 64 k bf16, XOR-swizzled
    char* psh = psh_all[w];
    const int swz = (l15 & 7) << 4;

    bf16x8 aq[2][2];
    #pragma unroll
    for (int m = 0; m < 2; ++m) {
        const size_t qoff = (size_t)(b * S_ + q0 + m * 16 + l15) * E_ + h * DH_;
        aq[m][0] = *(const bf16x8*)&q[qoff + lg * 8];
        aq[m][1] = *(const bf16x8*)&q[qoff + 32 + lg * 8];
    }

    float mrow[2] = {-1e30f, -1e30f};      // raw-scale running max (per q = l15, per m)
    float lrow[2] = {0.f, 0.f};
    f32x4 accO[2][4] = {};                 // O^T: lane holds d = dt*16+lg*4+r, q = l15 (+m*16)

    const bf16_t* kb = k + (size_t)b * S_ * E_ + h * DH_;
    const bf16_t* vb = vt + (size_t)(b * H_ + h) * DH_ * S_;
    const float sc = 0.125f * 1.44269504f;   // 1/sqrt(DH) * log2(e)

    for (int k0 = 0; k0 < S_; k0 += 64) {
        // ---- QK^T swapped: sf[m][n] = S^T[k = n*16+lg*4+r][q = m*16+l15] ----
        f32x4 sf[2][4];
        #pragma unroll
        for (int n = 0; n < 4; ++n) {
            const bf16_t* kr = kb + (size_t)(k0 + n * 16 + l15) * E_;
            bf16x8 bk0 = *(const bf16x8*)&kr[lg * 8];
            bf16x8 bk1 = *(const bf16x8*)&kr[32 + lg * 8];
            __builtin_amdgcn_s_setprio(1);
            #pragma unroll
            for (int m = 0; m < 2; ++m) {
                f32x4 s = {};
                s = __builtin_amdgcn_mfma_f32_16x16x32_bf16(bk0, aq[m][0], s, 0, 0, 0);
                s = __builtin_amdgcn_mfma_f32_16x16x32_bf16(bk1, aq[m][1], s, 0, 0, 0);
                sf[m][n] = s;
            }
            __builtin_amdgcn_s_setprio(0);
        }
        // ---- prefetch V (kk=0 half) so its latency hides under softmax ----
        bf16x8 v0[4];
        #pragma unroll
        for (int dt = 0; dt < 4; ++dt)
            v0[dt] = *(const bf16x8*)&vb[(size_t)(dt * 16 + l15) * S_ + k0 + lg * 8];

        // ---- softmax: in-lane reduce over 16 vals + 2 shfl over lg ----
        #pragma unroll
        for (int m = 0; m < 2; ++m) {
            float mx = sf[m][0][0];
            #pragma unroll
            for (int n = 0; n < 4; ++n)
                #pragma unroll
                for (int r = 0; r < 4; ++r) mx = fmaxf(mx, sf[m][n][r]);
            mx = fmaxf(mx, __shfl_xor(mx, 16, 64));
            mx = fmaxf(mx, __shfl_xor(mx, 32, 64));
            float mn = fmaxf(mrow[m], mx);
            float msc = mn * sc;
            float al = EXP2F(mrow[m] * sc - msc);
            float ps = 0.f;
            #pragma unroll
            for (int n = 0; n < 4; ++n) {
                bf16x4 pw;
                #pragma unroll
                for (int r = 0; r < 4; ++r) {
                    float pv = EXP2F(fmaf(sf[m][n][r], sc, -msc));
                    ps += pv;
                    pw[r] = (bf16_t)pv;
                }
                *(bf16x4*)(psh + (m * 16 + l15) * 128 + ((n * 32 + lg * 8) ^ swz)) = pw;
            }
            ps += __shfl_xor(ps, 16, 64);
            ps += __shfl_xor(ps, 32, 64);
            lrow[m] = lrow[m] * al + ps;
            mrow[m] = mn;
            #pragma unroll
            for (int dt = 0; dt < 4; ++dt) accO[m][dt] *= al;
        }
        asm volatile("" ::: "memory");   // order P ds_writes before pa ds_reads (same-wave LDS in-order)

        // ---- P back as B-operand; PV swapped: accO = Vt x P^T ----
        bf16x8 pa[2][2];
        #pragma unroll
        for (int m = 0; m < 2; ++m)
            #pragma unroll
            for (int kk = 0; kk < 2; ++kk)
                pa[m][kk] = *(const bf16x8*)(psh + (m * 16 + l15) * 128 + ((kk * 64 + lg * 16) ^ swz));
        bf16x8 v1[4];
        #pragma unroll
        for (int dt = 0; dt < 4; ++dt)
            v1[dt] = *(const bf16x8*)&vb[(size_t)(dt * 16 + l15) * S_ + k0 + 32 + lg * 8];
        __builtin_amdgcn_s_setprio(1);
        #pragma unroll
        for (int dt = 0; dt < 4; ++dt)
            #pragma unroll
            for (int m = 0; m < 2; ++m)
                accO[m][dt] = __builtin_amdgcn_mfma_f32_16x16x32_bf16(v0[dt], pa[m][0], accO[m][dt], 0, 0, 0);
        #pragma unroll
        for (int dt = 0; dt < 4; ++dt)
            #pragma unroll
            for (int m = 0; m < 2; ++m)
                accO[m][dt] = __builtin_amdgcn_mfma_f32_16x16x32_bf16(v1[dt], pa[m][1], accO[m][dt], 0, 0, 0);
        __builtin_amdgcn_s_setprio(0);
    }

    #pragma unroll
    for (int m = 0; m < 2; ++m) {
        float rl = 1.f / lrow[m];
        #pragma unroll
        for (int dt = 0; dt < 4; ++dt) {
            bf16x4 ov;
            #pragma unroll
            for (int r = 0; r < 4; ++r) ov[r] = (bf16_t)(accO[m][dt][r] * rl);
            *(bf16x4*)&o[(size_t)(b * S_ + q0 + m * 16 + l15) * E_ + h * DH_ + dt * 16 + lg * 4] = ov;
        }
    }
}

// ---------------- layernorm (fp32 in, fp32 + bf16 out), one wave per row ----------------
__launch_bounds__(256)
__global__ void ln_kernel(const float* __restrict__ in, const float* __restrict__ g,
                          const float* __restrict__ be, float* __restrict__ out32,
                          bf16_t* __restrict__ out16)
{
    int row = blockIdx.x * 4 + (threadIdx.x >> 6);
    int lane = threadIdx.x & 63;
    const float* rp = in + (size_t)row * E_ + lane * 8;
    float x[8];
    *(f32x4*)&x[0] = *(const f32x4*)rp;
    *(f32x4*)&x[4] = *(const f32x4*)(rp + 4);
    float s = 0.f;
    #pragma unroll
    for (int j = 0; j < 8; ++j) s += x[j];
    #pragma unroll
    for (int off = 32; off >= 1; off >>= 1) s += __shfl_xor(s, off, 64);
    float mean = s * (1.f / E_);
    float vs = 0.f;
    #pragma unroll
    for (int j = 0; j < 8; ++j) { float d = x[j] - mean; vs += d * d; }
    #pragma unroll
    for (int off = 32; off >= 1; off >>= 1) vs += __shfl_xor(vs, off, 64);
    float rstd = rsqrtf(vs * (1.f / E_) + 1e-5f);
    #pragma unroll
    for (int j = 0; j < 8; ++j) {
        int col = lane * 8 + j;
        float y = (x[j] - mean) * rstd * g[col] + be[col];
        size_t idx = (size_t)row * E_ + col;
        out32[idx] = y;
        out16[idx] = (bf16_t)y;
    }
}

// ---------------- final: LN + [E,2] head, one wave per row ----------------
__launch_bounds__(256)
__global__ void final_kernel(const float* __restrict__ in, const float* __restrict__ g,
                             const float* __restrict__ be, const float* __restrict__ Wout,
                             const float* __restrict__ bout, float* __restrict__ out)
{
    int row = blockIdx.x * 4 + (threadIdx.x >> 6);
    int lane = threadIdx.x & 63;
    const float* rp = in + (size_t)row * E_ + lane * 8;
    float x[8];
    *(f32x4*)&x[0] = *(const f32x4*)rp;
    *(f32x4*)&x[4] = *(const f32x4*)(rp + 4);
    float s = 0.f;
    #pragma unroll
    for (int j = 0; j < 8; ++j) s += x[j];
    #pragma unroll
    for (int off = 32; off >= 1; off >>= 1) s += __shfl_xor(s, off, 64);
    float mean = s * (1.f / E_);
    float vs = 0.f;
    #pragma unroll
    for (int j = 0; j < 8; ++j) { float d = x[j] - mean; vs += d * d; }
    #pragma unroll
    for (int off = 32; off >= 1; off >>= 1) vs += __shfl_xor(vs, off, 64);
    float rstd = rsqrtf(vs * (1.f / E_) + 1e-5f);
    float p0 = 0.f, p1 = 0.f;
    #pragma unroll
    for (int j = 0; j < 8; ++j) {
        int col = lane * 8 + j;
        float y = (x[j] - mean) * rstd * g[col] + be[col];
        p0 += y * Wout[col * 2 + 0];
        p1 += y * Wout[col * 2 + 1];
    }
    #pragma unroll
    for (int off = 32; off >= 1; off >>= 1) { p0 += __shfl_xor(p0, off, 64); p1 += __shfl_xor(p1, off, 64); }
    if (lane == 0) {
        out[(size_t)row * 2 + 0] = p0 + bout[0];
        out[(size_t)row * 2 + 1] = p1 + bout[1];
    }
}

extern "C" void kernel_launch(void* const* d_in, const int* in_sizes, int n_in,
                              void* d_out, int out_size, void* d_ws, size_t ws_size,
                              hipStream_t stream)
{
    (void)in_sizes; (void)n_in; (void)out_size;
    const float* x    = (const float*)d_in[0];
    const float* Win  = (const float*)d_in[1];
    const float* b_in = (const float*)d_in[2];
    const float* pe   = (const float*)d_in[3];
    const float* Wq   = (const float*)d_in[4];
    const float* bq   = (const float*)d_in[5];
    const float* Wk   = (const float*)d_in[6];
    const float* bk   = (const float*)d_in[7];
    const float* Wv   = (const float*)d_in[8];
    const float* bv   = (const float*)d_in[9];
    const float* Wo   = (const float*)d_in[10];
    const float* bo   = (const float*)d_in[11];
    const float* g1   = (const float*)d_in[12];
    const float* be1  = (const float*)d_in[13];
    const float* W1   = (const float*)d_in[14];
    const float* b1   = (const float*)d_in[15];
    const float* W2   = (const float*)d_in[16];
    const float* b2   = (const float*)d_in[17];
    const float* g2   = (const float*)d_in[18];
    const float* be2  = (const float*)d_in[19];
    const float* gf   = (const float*)d_in[20];
    const float* bef  = (const float*)d_in[21];
    const float* Wout = (const float*)d_in[22];
    const float* bout = (const float*)d_in[23];

    char* p = (char*)d_ws;
    auto take = [&](size_t bytes) { char* r = p; p += (bytes + 255) & ~(size_t)255; return r; };

    bf16_t* xb   = (bf16_t*)take((size_t)M_ * 64 * 2);
    bf16_t* WinT = (bf16_t*)take((size_t)E_ * 64 * 2);
    bf16_t* WqT  = (bf16_t*)take((size_t)L_ * E_ * E_ * 2);
    bf16_t* WkT  = (bf16_t*)take((size_t)L_ * E_ * E_ * 2);
    bf16_t* WvT  = (bf16_t*)take((size_t)L_ * E_ * E_ * 2);
    bf16_t* WoT  = (bf16_t*)take((size_t)L_ * E_ * E_ * 2);
    bf16_t* W1T  = (bf16_t*)take((size_t)L_ * E_ * F_ * 2);
    bf16_t* W2T  = (bf16_t*)take((size_t)L_ * E_ * F_ * 2);
    float*  h32  = (float*)take((size_t)M_ * E_ * 4);
    bf16_t* hb16 = (bf16_t*)take((size_t)M_ * E_ * 2);
    bf16_t* qb16 = (bf16_t*)take((size_t)M_ * E_ * 2);
    bf16_t* kb16 = (bf16_t*)take((size_t)M_ * E_ * 2);
    bf16_t* vtb  = (bf16_t*)take((size_t)M_ * E_ * 2);
    bf16_t* ob16 = (bf16_t*)take((size_t)M_ * E_ * 2);
    float*  t32  = (float*)take((size_t)M_ * E_ * 4);
    float*  a32  = (float*)take((size_t)M_ * E_ * 4);
    bf16_t* ab16 = (bf16_t*)take((size_t)M_ * E_ * 2);
    // overlay: q/k/vt/o (4 * M*E*2 == M*F*2 = 64MB, contiguous takes) are dead during the FFN
    bf16_t* f1b  = qb16;

    if ((size_t)(p - (char*)d_ws) > ws_size) return;

    cast_bf16_kernel<<<dim3(M_ * 64 / 4 / 256), dim3(256), 0, stream>>>(x, xb, M_ * 64);
    castT_kernel<<<dim3(E_ / 32, 64 / 32, 1), dim3(32, 8), 0, stream>>>(Win, WinT, 64, E_);
    castT_kernel<<<dim3(E_ / 32, E_ / 32, L_), dim3(32, 8), 0, stream>>>(Wq, WqT, E_, E_);
    castT_kernel<<<dim3(E_ / 32, E_ / 32, L_), dim3(32, 8), 0, stream>>>(Wk, WkT, E_, E_);
    castT_kernel<<<dim3(E_ / 32, E_ / 32, L_), dim3(32, 8), 0, stream>>>(Wv, WvT, E_, E_);
    castT_kernel<<<dim3(E_ / 32, E_ / 32, L_), dim3(32, 8), 0, stream>>>(Wo, WoT, E_, E_);
    castT_kernel<<<dim3(F_ / 32, E_ / 32, L_), dim3(32, 8), 0, stream>>>(W1, W1T, E_, F_);
    castT_kernel<<<dim3(E_ / 32, F_ / 32, L_), dim3(32, 8), 0, stream>>>(W2, W2T, F_, E_);

    gemm_kernel<1, false><<<dim3(M_ / 128, E_ / 128), dim3(256), 0, stream>>>(
        xb, WinT, b_in, h32, hb16, pe, M_, E_, 64);

    for (int i = 0; i < L_; ++i) {
        const bf16_t* WqTi = WqT + (size_t)i * E_ * E_;
        const bf16_t* WkTi = WkT + (size_t)i * E_ * E_;
        const bf16_t* WvTi = WvT + (size_t)i * E_ * E_;
        const bf16_t* WoTi = WoT + (size_t)i * E_ * E_;
        const bf16_t* W1Ti = W1T + (size_t)i * E_ * F_;
        const bf16_t* W2Ti = W2T + (size_t)i * E_ * F_;

        gemm_kernel<0, false><<<dim3(M_ / 128, E_ / 128), dim3(256), 0, stream>>>(
            hb16, WqTi, bq + i * E_, nullptr, qb16, nullptr, M_, E_, E_);
        gemm_kernel<0, false><<<dim3(M_ / 128, E_ / 128), dim3(256), 0, stream>>>(
            hb16, WkTi, bk + i * E_, nullptr, kb16, nullptr, M_, E_, E_);
        gemm_kernel<3, false><<<dim3(M_ / 128, E_ / 128), dim3(256), 0, stream>>>(
            hb16, WvTi, bv + i * E_, nullptr, vtb, nullptr, M_, E_, E_);
        attn_kernel<<<dim3(1024), dim3(256), 0, stream>>>(qb16, kb16, vtb, ob16);
        gemm_kernel<2, false><<<dim3(M_ / 128, E_ / 128), dim3(256), 0, stream>>>(
            ob16, WoTi, bo + i * E_, t32, nullptr, h32, M_, E_, E_);
        ln_kernel<<<dim3(M_ / 4), dim3(256), 0, stream>>>(t32, g1 + i * E_, be1 + i * E_, a32, ab16);
        gemm_kernel<0, true><<<dim3(M_ / 128, F_ / 128), dim3(256), 0, stream>>>(
            ab16, W1Ti, b1 + i * F_, nullptr, f1b, nullptr, M_, F_, E_);
        gemm_kernel<2, false><<<dim3(M_ / 128, E_ / 128), dim3(256), 0, stream>>>(
            f1b, W2Ti, b2 + i * E_, t32, nullptr, a32, M_, E_, F_);
        ln_kernel<<<dim3(M_ / 4), dim3(256), 0, stream>>>(t32, g2 + i * E_, be2 + i * E_, h32, hb16);
    }

    final_kernel<<<dim3(M_ / 4), dim3(256), 0, stream>>>(h32, gf, bef, Wout, bout, (float*)d_out);
}